// Round 20
// baseline (171.519 us; speedup 1.0000x reference)
//
#include <hip/hip_runtime.h>
#include <math.h>

#define BB 64
#define T_SUB 512
#define WW 256
#define DD 768
#define HH 20
#define CAP_DIM 10
#define IN_DIM 778
#define KPAD 800
#define G4 80     // 4*H
#define NOUT 160
#define LOG2E 1.44269504f

typedef _Float16 f16x8 __attribute__((ext_vector_type(8)));
typedef float f32x4 __attribute__((ext_vector_type(4)));
typedef unsigned int uint2v __attribute__((ext_vector_type(2)));

// ws layout (bytes):
//   wpad : [160][800] f16   @ 0          (256,000 B)  -- PRE-SCALED by log2e
//   x    : [16384][800] f16 @ 387,072    (26,214,400 B)
#define WP_OFF   ((size_t)0)
#define X_OFF    ((size_t)387072)

// ---------------- K0: pad+scale weights (160 blocks only) -------------------
__global__ __launch_bounds__(256) void k_prep(
    const float* __restrict__ wf, const float* __restrict__ wb,
    _Float16* __restrict__ wp)
{
    int j = blockIdx.x;
    const float* src = (j < G4) ? (wf + (size_t)j * IN_DIM)
                                : (wb + (size_t)(j - G4) * IN_DIM);
    for (int k = threadIdx.x; k < KPAD; k += 256)
        wp[(size_t)j * KPAD + k] = (k < IN_DIM) ? (_Float16)(LOG2E * src[k])
                                                : (_Float16)0.f;
}

// ---------------- K1: streaming mean -> fp16 x ------------------------------
// Seg bounds computed per-block (<=7 words) in LDS; hiddens loads NON-TEMPORAL
// (zero reuse -> keep the 302 MB stream out of L2's retention path).
__device__ __forceinline__ f32x4 ntl(const float* p) {
    return __builtin_nontemporal_load((const f32x4*)p);
}

__global__ __launch_bounds__(256) void k_mean(
    const float* __restrict__ hiddens, const int* __restrict__ b2t,
    const int* __restrict__ cap_inds, const float* __restrict__ cap_table,
    _Float16* __restrict__ x)
{
    __shared__ int2 segs[8];
    int wb0 = (blockIdx.x * 256) / 50;
    int nw  = (blockIdx.x * 256 + 255) / 50 - wb0 + 1;   // <= 7
    if (threadIdx.x < nw) {
        int bw_ = wb0 + threadIdx.x;
        int b_ = bw_ >> 8, w_ = bw_ & 255;
        const int* row = b2t + (size_t)b_ * T_SUB;
        int lo = 0, hi = T_SUB;
        while (lo < hi) { int m = (lo + hi) >> 1; if (row[m] < w_) lo = m + 1; else hi = m; }
        int lo2 = lo, hi2 = T_SUB;
        while (lo2 < hi2) { int m = (lo2 + hi2) >> 1; if (row[m] < w_ + 1) lo2 = m + 1; else hi2 = m; }
        segs[threadIdx.x] = make_int2(lo, lo2 - lo);
    }
    __syncthreads();

    int idx = blockIdx.x * 256 + threadIdx.x;   // 16384*50 total
    int d2 = idx % 50;
    int bw = idx / 50;
    int b = bw >> 8;
    int2 sg = segs[bw - wb0];
    int lo = sg.x, cnt = sg.y;
    const size_t LSTR = (size_t)BB * (T_SUB + 1) * DD;
    const float* rowp = hiddens + ((size_t)b * (T_SUB + 1) + lo + 1) * DD;
    float inv = 1.0f / (3.0f * (float)(cnt > 0 ? cnt : 1));
    bool bmean = (d2 + 50) < 96;
    f16x8 ra, rb;

    if (cnt == 2 && bmean) {
        // all 24 nt loads issued up-front (unrolled, independent)
        const float* pa  = rowp + d2 * 8;
        const float* pb_ = rowp + (d2 + 50) * 8;
        f32x4 A[12], B[12];
#pragma unroll
        for (int l = 0; l < 3; ++l) {
            A[l*4+0] = ntl(pa + l*LSTR);        A[l*4+1] = ntl(pa + l*LSTR + 4);
            A[l*4+2] = ntl(pa + l*LSTR + DD);   A[l*4+3] = ntl(pa + l*LSTR + DD + 4);
            B[l*4+0] = ntl(pb_ + l*LSTR);       B[l*4+1] = ntl(pb_ + l*LSTR + 4);
            B[l*4+2] = ntl(pb_ + l*LSTR + DD);  B[l*4+3] = ntl(pb_ + l*LSTR + DD + 4);
        }
#pragma unroll
        for (int q = 0; q < 4; q++) {
            ra[q]     = (_Float16)((A[0][q]+A[2][q]+A[4][q]+A[6][q]+A[8][q]+A[10][q]) * inv);
            ra[q + 4] = (_Float16)((A[1][q]+A[3][q]+A[5][q]+A[7][q]+A[9][q]+A[11][q]) * inv);
            rb[q]     = (_Float16)((B[0][q]+B[2][q]+B[4][q]+B[6][q]+B[8][q]+B[10][q]) * inv);
            rb[q + 4] = (_Float16)((B[1][q]+B[3][q]+B[5][q]+B[7][q]+B[9][q]+B[11][q]) * inv);
        }
    } else {
        float a[8], bacc[8];
#pragma unroll
        for (int q = 0; q < 8; q++) { a[q] = 0.f; bacc[q] = 0.f; }
        for (int l = 0; l < 3; ++l)
            for (int ti = 0; ti < cnt; ++ti) {
                const float* p = rowp + l * LSTR + (size_t)ti * DD;
                f32x4 v0 = ntl(p + d2 * 8);
                f32x4 v1 = ntl(p + d2 * 8 + 4);
#pragma unroll
                for (int q = 0; q < 4; q++) { a[q] += v0[q]; a[q+4] += v1[q]; }
                if (bmean) {
                    f32x4 u0 = ntl(p + (d2 + 50) * 8);
                    f32x4 u1 = ntl(p + (d2 + 50) * 8 + 4);
#pragma unroll
                    for (int q = 0; q < 4; q++) { bacc[q] += u0[q]; bacc[q+4] += u1[q]; }
                }
            }
#pragma unroll
        for (int q = 0; q < 8; q++) { ra[q] = (_Float16)(a[q] * inv); rb[q] = (_Float16)(bacc[q] * inv); }
    }
    if (!bmean) {
        int ci = cap_inds[bw];
#pragma unroll
        for (int q = 0; q < 8; q++) {
            int c = (d2 + 50 - 96) * 8 + q;
            rb[q] = (c < CAP_DIM) ? (_Float16)cap_table[ci * CAP_DIM + c] : (_Float16)0.f;
        }
    }
    *(f16x8*)(x + (size_t)bw * KPAD + d2 * 8) = ra;
    *(f16x8*)(x + (size_t)bw * KPAD + (d2 + 50) * 8) = rb;
}

// ---------------- K2: FUSED gemm+LSTM, all-chunks-upfront, solo chain -------
__device__ __forceinline__ float xchg32(float v) {
    unsigned int a = __float_as_uint(v);
    uint2v r = __builtin_amdgcn_permlane32_swap(a, a, false, false);
    return __uint_as_float(r[0] ^ r[1] ^ a);   // partner lane's value (lane ^ 32)
}
__device__ __forceinline__ float fex2(float v) { return __builtin_amdgcn_exp2f(v); }
__device__ __forceinline__ float frcp(float v) { return __builtin_amdgcn_rcpf(v); }
__device__ __forceinline__ float rl(float v, int k) {
    return __uint_as_float(__builtin_amdgcn_readlane(__float_as_uint(v), k));
}

__global__ __launch_bounds__(320) void k_lstm(
    const _Float16* __restrict__ x, const _Float16* __restrict__ wp,
    const float* __restrict__ bias_f, const float* __restrict__ bias_b,
    const float* __restrict__ whh_f, const float* __restrict__ whh_b,
    float* __restrict__ out)
{
    __shared__ _Float16 gb[WW * G4];     // 40 KB: all 256 words' gates (f16)
    int dir  = blockIdx.x >> 6;
    int b    = blockIdx.x & 63;
    int t    = threadIdx.x;
    int wv   = t >> 6;
    int lane = t & 63;

    if (wv >= 1) {
        // ---- gemm: wave wv owns words [64*(wv-1), 64*wv), all 4 mtiles ----
        int col  = lane & 15;
        int koff = (lane >> 4) * 8;
        int wbase = (wv - 1) * 64;
        const _Float16* bp = wp + (size_t)(dir * G4 + col) * KPAD + koff;
        float bias_v[5];
#pragma unroll
        for (int nf = 0; nf < 5; nf++)
            bias_v[nf] = LOG2E * (dir ? bias_b : bias_f)[nf * 16 + col];
        f32x4 acc[4][5];
#pragma unroll
        for (int mt = 0; mt < 4; mt++)
#pragma unroll
            for (int nf = 0; nf < 5; nf++)
#pragma unroll
                for (int r = 0; r < 4; r++) acc[mt][nf][r] = 0.f;
        for (int k0 = 0; k0 < KPAD; k0 += 32) {
            f16x8 bf[5];
#pragma unroll
            for (int nf = 0; nf < 5; nf++)
                bf[nf] = *(const f16x8*)(bp + (size_t)nf * 16 * KPAD + k0);
#pragma unroll
            for (int mt = 0; mt < 4; mt++) {
                int arow = b * 256 + wbase + mt * 16 + (lane & 15);
                f16x8 af = *(const f16x8*)(x + (size_t)arow * KPAD + koff + k0);
#pragma unroll
                for (int nf = 0; nf < 5; nf++)
                    acc[mt][nf] = __builtin_amdgcn_mfma_f32_16x16x32_f16(af, bf[nf], acc[mt][nf], 0, 0, 0);
            }
        }
        // C/D: col=lane&15, row=(lane>>4)*4+reg [m89]. Permute cols + bias.
#pragma unroll
        for (int mt = 0; mt < 4; mt++)
#pragma unroll
            for (int nf = 0; nf < 5; nf++) {
                int g = nf * 16 + col;
                int pcol = (g % 40) * 2 + (g / 40);
#pragma unroll
                for (int r = 0; r < 4; r++) {
                    int word = wbase + mt * 16 + (lane >> 4) * 4 + r;
                    gb[word * G4 + pcol] = (_Float16)(acc[mt][nf][r] + bias_v[nf]);
                }
            }
        __syncthreads();   // single barrier; gemm waves exit
        return;
    }

    // ---- wave 0: recurrence constants ----
    const float* whh = dir ? whh_b : whh_f;
    int j = lane & 31; if (j > 19) j = 19;
    bool low = lane < 32;
    float mm = low ? 1.f : 2.f;
    float aa = low ? 0.f : -1.f;
    int coff = low ? (40 + 2 * j) : (2 * j);   // (f,o) | (i,g) pair, f16x2
    float w0[HH], w1[HH];
    {
        int r0 = low ? (20 + j) : j;
        int r1 = low ? (60 + j) : (40 + j);
#pragma unroll
        for (int k = 0; k < HH; k++) {
            w0[k] = LOG2E * whh[r0 * HH + k];
            w1[k] = LOG2E * whh[r1 * HH + k];
        }
    }
    __syncthreads();       // gates ready

    __builtin_amdgcn_s_setprio(1);
    const float TCM = -2.f * LOG2E;
    float h = 0.f, c = 0.f;
    int w = dir ? (WW - 1) : 0;
    int stepd = dir ? -1 : 1;

    union { unsigned int u; _Float16 hx[2]; } cu;
    cu.u = *(const unsigned int*)(gb + w * G4 + coff);
    float2 pre = make_float2((float)cu.hx[0], (float)cu.hx[1]);

    for (int sl = 0; sl < WW; ++sl) {
        int wn = w + stepd;
        int wnc = wn < 0 ? 0 : (wn > 255 ? 255 : wn);
        union { unsigned int u; _Float16 hx[2]; } nu;
        nu.u = *(const unsigned int*)(gb + wnc * G4 + coff);   // prefetch
        // 4-way split dot: 5-deep FMA chains
        float s0 = pre.x, s1 = 0.f, s2 = 0.f, s3 = 0.f;
        float t0 = pre.y, t1 = 0.f, t2 = 0.f, t3 = 0.f;
#pragma unroll
        for (int k = 0; k < 5; k++) {
            float h0 = rl(h, k), h1 = rl(h, k + 5), h2 = rl(h, k + 10), h3 = rl(h, k + 15);
            s0 = fmaf(h0, w0[k],      s0);  s1 = fmaf(h1, w0[k + 5],  s1);
            s2 = fmaf(h2, w0[k + 10], s2);  s3 = fmaf(h3, w0[k + 15], s3);
            t0 = fmaf(h0, w1[k],      t0);  t1 = fmaf(h1, w1[k + 5],  t1);
            t2 = fmaf(h2, w1[k + 10], t2);  t3 = fmaf(h3, w1[k + 15], t3);
        }
        float a0 = (s0 + s1) + (s2 + s3);
        float a1 = (t0 + t1) + (t2 + t3);
        float u0 = frcp(1.f + fex2(-a0));              // sig(f) | sig(i)
        float uu = frcp(1.f + fex2(-mm * a1));
        float u1 = fmaf(uu, mm, aa);                   // sig(o) | tanh(g)
        float p  = u0 * u1;
        float ps = xchg32(p);                          // low gets sig(i)*tanh(g)
        c = fmaf(u0, c, ps);
        float tc = fmaf(2.f, frcp(1.f + fex2(TCM * c)), -1.f);  // tanh(c)
        h = u1 * tc;
        if (lane < HH)
            out[((size_t)b * WW + w) * (2 * HH) + dir * HH + lane] = h;
        pre = make_float2((float)nu.hx[0], (float)nu.hx[1]);
        w = wn;
    }
    __builtin_amdgcn_s_setprio(0);
}

extern "C" void kernel_launch(void* const* d_in, const int* in_sizes, int n_in,
                              void* d_out, int out_size, void* d_ws, size_t ws_size,
                              hipStream_t stream) {
    const float* hiddens   = (const float*)d_in[0];
    const int*   bert2toks = (const int*)d_in[1];
    const int*   cap_inds  = (const int*)d_in[2];
    const float* cap_table = (const float*)d_in[3];
    const float* w_ih_f    = (const float*)d_in[4];
    const float* w_hh_f    = (const float*)d_in[5];
    const float* b_f       = (const float*)d_in[6];
    const float* w_ih_b    = (const float*)d_in[7];
    const float* w_hh_b    = (const float*)d_in[8];
    const float* b_b       = (const float*)d_in[9];
    float* out = (float*)d_out;

    _Float16* wpad = (_Float16*)((char*)d_ws + WP_OFF);
    _Float16* x    = (_Float16*)((char*)d_ws + X_OFF);

    k_prep<<<NOUT, 256, 0, stream>>>(w_ih_f, w_ih_b, wpad);
    k_mean<<<(BB * WW * 50) / 256, 256, 0, stream>>>(hiddens, bert2toks, cap_inds, cap_table, x);
    k_lstm<<<128, 320, 0, stream>>>(x, wpad, b_f, b_b, w_hh_f, w_hh_b, out);
}

// Round 21
// 146.839 us; speedup vs baseline: 1.1681x; 1.1681x over previous
//
#include <hip/hip_runtime.h>
#include <math.h>

#define BB 64
#define T_SUB 512
#define WW 256
#define DD 768
#define HH 20
#define CAP_DIM 10
#define IN_DIM 778
#define KPAD 800
#define G4 80     // 4*H
#define NOUT 160
#define LOG2E 1.44269504f

typedef _Float16 f16x8 __attribute__((ext_vector_type(8)));
typedef float f32x4 __attribute__((ext_vector_type(4)));
typedef unsigned int uint2v __attribute__((ext_vector_type(2)));

// ws layout (bytes):
//   wpad : [160][800] f16   @ 0          (256,000 B)  -- PRE-SCALED by log2e
//   x    : [16384][800] f16 @ 387,072    (26,214,400 B)
#define WP_OFF   ((size_t)0)
#define X_OFF    ((size_t)387072)

// ---------------- K0: pad+scale weights (160 blocks only) -------------------
__global__ __launch_bounds__(256) void k_prep(
    const float* __restrict__ wf, const float* __restrict__ wb,
    _Float16* __restrict__ wp)
{
    int j = blockIdx.x;
    const float* src = (j < G4) ? (wf + (size_t)j * IN_DIM)
                                : (wb + (size_t)(j - G4) * IN_DIM);
    for (int k = threadIdx.x; k < KPAD; k += 256)
        wp[(size_t)j * KPAD + k] = (k < IN_DIM) ? (_Float16)(LOG2E * src[k])
                                                : (_Float16)0.f;
}

// ---------------- K1: streaming mean -> fp16 x ------------------------------
// Seg bounds per-block in LDS (<=7 searches by 7 threads, once per block).
// PLAIN cached loads (R20's non-temporal hint collapsed read BW ~1/3 —
// neighboring threads share cache-line sectors; nt defeats the L2 merge).
__global__ __launch_bounds__(256) void k_mean(
    const float* __restrict__ hiddens, const int* __restrict__ b2t,
    const int* __restrict__ cap_inds, const float* __restrict__ cap_table,
    _Float16* __restrict__ x)
{
    __shared__ int2 segs[8];
    int wb0 = (blockIdx.x * 256) / 50;
    int nw  = (blockIdx.x * 256 + 255) / 50 - wb0 + 1;   // <= 7
    if (threadIdx.x < nw) {
        int bw_ = wb0 + threadIdx.x;
        int b_ = bw_ >> 8, w_ = bw_ & 255;
        const int* row = b2t + (size_t)b_ * T_SUB;
        int lo = 0, hi = T_SUB;
        while (lo < hi) { int m = (lo + hi) >> 1; if (row[m] < w_) lo = m + 1; else hi = m; }
        int lo2 = lo, hi2 = T_SUB;
        while (lo2 < hi2) { int m = (lo2 + hi2) >> 1; if (row[m] < w_ + 1) lo2 = m + 1; else hi2 = m; }
        segs[threadIdx.x] = make_int2(lo, lo2 - lo);
    }
    __syncthreads();

    int idx = blockIdx.x * 256 + threadIdx.x;   // 16384*50 total
    int d2 = idx % 50;
    int bw = idx / 50;
    int b = bw >> 8;
    int2 sg = segs[bw - wb0];
    int lo = sg.x, cnt = sg.y;
    const size_t LSTR = (size_t)BB * (T_SUB + 1) * DD;
    const float* rowp = hiddens + ((size_t)b * (T_SUB + 1) + lo + 1) * DD;
    float inv = 1.0f / (3.0f * (float)(cnt > 0 ? cnt : 1));
    bool bmean = (d2 + 50) < 96;
    f16x8 ra, rb;

    if (cnt == 2 && bmean) {
        const float* pa  = rowp + d2 * 8;
        const float* pb_ = rowp + (d2 + 50) * 8;
        float4 A0 = *(const float4*)(pa);                float4 A1 = *(const float4*)(pa + 4);
        float4 A2 = *(const float4*)(pa + DD);           float4 A3 = *(const float4*)(pa + DD + 4);
        float4 A4 = *(const float4*)(pa + LSTR);         float4 A5 = *(const float4*)(pa + LSTR + 4);
        float4 A6 = *(const float4*)(pa + LSTR + DD);    float4 A7 = *(const float4*)(pa + LSTR + DD + 4);
        float4 A8 = *(const float4*)(pa + 2*LSTR);       float4 A9 = *(const float4*)(pa + 2*LSTR + 4);
        float4 Aa = *(const float4*)(pa + 2*LSTR + DD);  float4 Ab = *(const float4*)(pa + 2*LSTR + DD + 4);
        float4 B0 = *(const float4*)(pb_);               float4 B1 = *(const float4*)(pb_ + 4);
        float4 B2 = *(const float4*)(pb_ + DD);          float4 B3 = *(const float4*)(pb_ + DD + 4);
        float4 B4 = *(const float4*)(pb_ + LSTR);        float4 B5 = *(const float4*)(pb_ + LSTR + 4);
        float4 B6 = *(const float4*)(pb_ + LSTR + DD);   float4 B7 = *(const float4*)(pb_ + LSTR + DD + 4);
        float4 B8 = *(const float4*)(pb_ + 2*LSTR);      float4 B9 = *(const float4*)(pb_ + 2*LSTR + 4);
        float4 Ba = *(const float4*)(pb_ + 2*LSTR + DD); float4 Bb = *(const float4*)(pb_ + 2*LSTR + DD + 4);
        ra[0] = (_Float16)((A0.x+A2.x+A4.x+A6.x+A8.x+Aa.x) * inv);
        ra[1] = (_Float16)((A0.y+A2.y+A4.y+A6.y+A8.y+Aa.y) * inv);
        ra[2] = (_Float16)((A0.z+A2.z+A4.z+A6.z+A8.z+Aa.z) * inv);
        ra[3] = (_Float16)((A0.w+A2.w+A4.w+A6.w+A8.w+Aa.w) * inv);
        ra[4] = (_Float16)((A1.x+A3.x+A5.x+A7.x+A9.x+Ab.x) * inv);
        ra[5] = (_Float16)((A1.y+A3.y+A5.y+A7.y+A9.y+Ab.y) * inv);
        ra[6] = (_Float16)((A1.z+A3.z+A5.z+A7.z+A9.z+Ab.z) * inv);
        ra[7] = (_Float16)((A1.w+A3.w+A5.w+A7.w+A9.w+Ab.w) * inv);
        rb[0] = (_Float16)((B0.x+B2.x+B4.x+B6.x+B8.x+Ba.x) * inv);
        rb[1] = (_Float16)((B0.y+B2.y+B4.y+B6.y+B8.y+Ba.y) * inv);
        rb[2] = (_Float16)((B0.z+B2.z+B4.z+B6.z+B8.z+Ba.z) * inv);
        rb[3] = (_Float16)((B0.w+B2.w+B4.w+B6.w+B8.w+Ba.w) * inv);
        rb[4] = (_Float16)((B1.x+B3.x+B5.x+B7.x+B9.x+Bb.x) * inv);
        rb[5] = (_Float16)((B1.y+B3.y+B5.y+B7.y+B9.y+Bb.y) * inv);
        rb[6] = (_Float16)((B1.z+B3.z+B5.z+B7.z+B9.z+Bb.z) * inv);
        rb[7] = (_Float16)((B1.w+B3.w+B5.w+B7.w+B9.w+Bb.w) * inv);
    } else {
        float a[8], bacc[8];
#pragma unroll
        for (int q = 0; q < 8; q++) { a[q] = 0.f; bacc[q] = 0.f; }
        for (int l = 0; l < 3; ++l)
            for (int ti = 0; ti < cnt; ++ti) {
                const float* p = rowp + l * LSTR + (size_t)ti * DD;
                float4 v0 = *(const float4*)(p + d2 * 8);
                float4 v1 = *(const float4*)(p + d2 * 8 + 4);
                a[0]+=v0.x; a[1]+=v0.y; a[2]+=v0.z; a[3]+=v0.w;
                a[4]+=v1.x; a[5]+=v1.y; a[6]+=v1.z; a[7]+=v1.w;
                if (bmean) {
                    float4 u0 = *(const float4*)(p + (d2 + 50) * 8);
                    float4 u1 = *(const float4*)(p + (d2 + 50) * 8 + 4);
                    bacc[0]+=u0.x; bacc[1]+=u0.y; bacc[2]+=u0.z; bacc[3]+=u0.w;
                    bacc[4]+=u1.x; bacc[5]+=u1.y; bacc[6]+=u1.z; bacc[7]+=u1.w;
                }
            }
#pragma unroll
        for (int q = 0; q < 8; q++) { ra[q] = (_Float16)(a[q] * inv); rb[q] = (_Float16)(bacc[q] * inv); }
    }
    if (!bmean) {
        int ci = cap_inds[bw];
#pragma unroll
        for (int q = 0; q < 8; q++) {
            int c = (d2 + 50 - 96) * 8 + q;
            rb[q] = (c < CAP_DIM) ? (_Float16)cap_table[ci * CAP_DIM + c] : (_Float16)0.f;
        }
    }
    *(f16x8*)(x + (size_t)bw * KPAD + d2 * 8) = ra;
    *(f16x8*)(x + (size_t)bw * KPAD + (d2 + 50) * 8) = rb;
}

// ---------------- K2: FUSED gemm+LSTM, all-chunks-upfront, solo chain -------
__device__ __forceinline__ float xchg32(float v) {
    unsigned int a = __float_as_uint(v);
    uint2v r = __builtin_amdgcn_permlane32_swap(a, a, false, false);
    return __uint_as_float(r[0] ^ r[1] ^ a);   // partner lane's value (lane ^ 32)
}
__device__ __forceinline__ float fex2(float v) { return __builtin_amdgcn_exp2f(v); }
__device__ __forceinline__ float frcp(float v) { return __builtin_amdgcn_rcpf(v); }
__device__ __forceinline__ float rl(float v, int k) {
    return __uint_as_float(__builtin_amdgcn_readlane(__float_as_uint(v), k));
}

__global__ __launch_bounds__(320) void k_lstm(
    const _Float16* __restrict__ x, const _Float16* __restrict__ wp,
    const float* __restrict__ bias_f, const float* __restrict__ bias_b,
    const float* __restrict__ whh_f, const float* __restrict__ whh_b,
    float* __restrict__ out)
{
    __shared__ _Float16 gb[WW * G4];     // 40 KB: all 256 words' gates (f16)
    int dir  = blockIdx.x >> 6;
    int b    = blockIdx.x & 63;
    int t    = threadIdx.x;
    int wv   = t >> 6;
    int lane = t & 63;

    if (wv >= 1) {
        // ---- gemm: wave wv owns words [64*(wv-1), 64*wv), all 4 mtiles ----
        int col  = lane & 15;
        int koff = (lane >> 4) * 8;
        int wbase = (wv - 1) * 64;
        const _Float16* bp = wp + (size_t)(dir * G4 + col) * KPAD + koff;
        float bias_v[5];
#pragma unroll
        for (int nf = 0; nf < 5; nf++)
            bias_v[nf] = LOG2E * (dir ? bias_b : bias_f)[nf * 16 + col];
        f32x4 acc[4][5];
#pragma unroll
        for (int mt = 0; mt < 4; mt++)
#pragma unroll
            for (int nf = 0; nf < 5; nf++)
#pragma unroll
                for (int r = 0; r < 4; r++) acc[mt][nf][r] = 0.f;
        for (int k0 = 0; k0 < KPAD; k0 += 32) {
            f16x8 bf[5];
#pragma unroll
            for (int nf = 0; nf < 5; nf++)
                bf[nf] = *(const f16x8*)(bp + (size_t)nf * 16 * KPAD + k0);
#pragma unroll
            for (int mt = 0; mt < 4; mt++) {
                int arow = b * 256 + wbase + mt * 16 + (lane & 15);
                f16x8 af = *(const f16x8*)(x + (size_t)arow * KPAD + koff + k0);
#pragma unroll
                for (int nf = 0; nf < 5; nf++)
                    acc[mt][nf] = __builtin_amdgcn_mfma_f32_16x16x32_f16(af, bf[nf], acc[mt][nf], 0, 0, 0);
            }
        }
        // C/D: col=lane&15, row=(lane>>4)*4+reg [m89]. Permute cols + bias.
#pragma unroll
        for (int mt = 0; mt < 4; mt++)
#pragma unroll
            for (int nf = 0; nf < 5; nf++) {
                int g = nf * 16 + col;
                int pcol = (g % 40) * 2 + (g / 40);
#pragma unroll
                for (int r = 0; r < 4; r++) {
                    int word = wbase + mt * 16 + (lane >> 4) * 4 + r;
                    gb[word * G4 + pcol] = (_Float16)(acc[mt][nf][r] + bias_v[nf]);
                }
            }
        __syncthreads();   // single barrier; gemm waves exit
        return;
    }

    // ---- wave 0: recurrence constants ----
    const float* whh = dir ? whh_b : whh_f;
    int j = lane & 31; if (j > 19) j = 19;
    bool low = lane < 32;
    float mm = low ? 1.f : 2.f;
    float aa = low ? 0.f : -1.f;
    int coff = low ? (40 + 2 * j) : (2 * j);   // (f,o) | (i,g) pair, f16x2
    float w0[HH], w1[HH];
    {
        int r0 = low ? (20 + j) : j;
        int r1 = low ? (60 + j) : (40 + j);
#pragma unroll
        for (int k = 0; k < HH; k++) {
            w0[k] = LOG2E * whh[r0 * HH + k];
            w1[k] = LOG2E * whh[r1 * HH + k];
        }
    }
    __syncthreads();       // gates ready

    __builtin_amdgcn_s_setprio(1);
    const float TCM = -2.f * LOG2E;
    float h = 0.f, c = 0.f;
    int w = dir ? (WW - 1) : 0;
    int stepd = dir ? -1 : 1;

    union { unsigned int u; _Float16 hx[2]; } cu;
    cu.u = *(const unsigned int*)(gb + w * G4 + coff);
    float2 pre = make_float2((float)cu.hx[0], (float)cu.hx[1]);

    for (int sl = 0; sl < WW; ++sl) {
        int wn = w + stepd;
        int wnc = wn < 0 ? 0 : (wn > 255 ? 255 : wn);
        union { unsigned int u; _Float16 hx[2]; } nu;
        nu.u = *(const unsigned int*)(gb + wnc * G4 + coff);   // prefetch
        // 4-way split dot: 5-deep FMA chains
        float s0 = pre.x, s1 = 0.f, s2 = 0.f, s3 = 0.f;
        float t0 = pre.y, t1 = 0.f, t2 = 0.f, t3 = 0.f;
#pragma unroll
        for (int k = 0; k < 5; k++) {
            float h0 = rl(h, k), h1 = rl(h, k + 5), h2 = rl(h, k + 10), h3 = rl(h, k + 15);
            s0 = fmaf(h0, w0[k],      s0);  s1 = fmaf(h1, w0[k + 5],  s1);
            s2 = fmaf(h2, w0[k + 10], s2);  s3 = fmaf(h3, w0[k + 15], s3);
            t0 = fmaf(h0, w1[k],      t0);  t1 = fmaf(h1, w1[k + 5],  t1);
            t2 = fmaf(h2, w1[k + 10], t2);  t3 = fmaf(h3, w1[k + 15], t3);
        }
        float a0 = (s0 + s1) + (s2 + s3);
        float a1 = (t0 + t1) + (t2 + t3);
        float u0 = frcp(1.f + fex2(-a0));              // sig(f) | sig(i)
        float uu = frcp(1.f + fex2(-mm * a1));
        float u1 = fmaf(uu, mm, aa);                   // sig(o) | tanh(g)
        float p  = u0 * u1;
        float ps = xchg32(p);                          // low gets sig(i)*tanh(g)
        c = fmaf(u0, c, ps);
        float tc = fmaf(2.f, frcp(1.f + fex2(TCM * c)), -1.f);  // tanh(c)
        h = u1 * tc;
        if (lane < HH)
            out[((size_t)b * WW + w) * (2 * HH) + dir * HH + lane] = h;
        pre = make_float2((float)nu.hx[0], (float)nu.hx[1]);
        w = wn;
    }
    __builtin_amdgcn_s_setprio(0);
}

extern "C" void kernel_launch(void* const* d_in, const int* in_sizes, int n_in,
                              void* d_out, int out_size, void* d_ws, size_t ws_size,
                              hipStream_t stream) {
    const float* hiddens   = (const float*)d_in[0];
    const int*   bert2toks = (const int*)d_in[1];
    const int*   cap_inds  = (const int*)d_in[2];
    const float* cap_table = (const float*)d_in[3];
    const float* w_ih_f    = (const float*)d_in[4];
    const float* w_hh_f    = (const float*)d_in[5];
    const float* b_f       = (const float*)d_in[6];
    const float* w_ih_b    = (const float*)d_in[7];
    const float* w_hh_b    = (const float*)d_in[8];
    const float* b_b       = (const float*)d_in[9];
    float* out = (float*)d_out;

    _Float16* wpad = (_Float16*)((char*)d_ws + WP_OFF);
    _Float16* x    = (_Float16*)((char*)d_ws + X_OFF);

    k_prep<<<NOUT, 256, 0, stream>>>(w_ih_f, w_ih_b, wpad);
    k_mean<<<(BB * WW * 50) / 256, 256, 0, stream>>>(hiddens, bert2toks, cap_inds, cap_table, x);
    k_lstm<<<128, 320, 0, stream>>>(x, wpad, b_f, b_b, w_hh_f, w_hh_b, out);
}

// Round 22
// 138.743 us; speedup vs baseline: 1.2362x; 1.0584x over previous
//
#include <hip/hip_runtime.h>
#include <math.h>

#define BB 64
#define T_SUB 512
#define WW 256
#define DD 768
#define HH 20
#define CAP_DIM 10
#define IN_DIM 778
#define KPAD 800
#define G4 80     // 4*H
#define NOUT 160
#define LOG2E 1.44269504f

typedef _Float16 f16x8 __attribute__((ext_vector_type(8)));
typedef float f32x4 __attribute__((ext_vector_type(4)));
typedef unsigned int uint2v __attribute__((ext_vector_type(2)));

// ws layout (bytes):
//   wpad : [160][800] f16   @ 0          (256,000 B)  -- PRE-SCALED by log2e
//   seg  : int2[16384]      @ 256,000    (131,072 B)
//   x    : [16384][800] f16 @ 387,072    (26,214,400 B)
#define WP_OFF   ((size_t)0)
#define SEG_OFF  ((size_t)256000)
#define X_OFF    ((size_t)387072)

// ---------------- K0: pad+scale weights (0..159) + segment search (160..223)
__global__ __launch_bounds__(256) void k_prep(
    const float* __restrict__ wf, const float* __restrict__ wb,
    const int* __restrict__ b2t,
    _Float16* __restrict__ wp, int2* __restrict__ seg)
{
    int blk = blockIdx.x;
    if (blk < NOUT) {
        int j = blk;
        const float* src = (j < G4) ? (wf + (size_t)j * IN_DIM)
                                    : (wb + (size_t)(j - G4) * IN_DIM);
        for (int k = threadIdx.x; k < KPAD; k += 256)
            wp[(size_t)j * KPAD + k] = (k < IN_DIM) ? (_Float16)(LOG2E * src[k])
                                                    : (_Float16)0.f;
    } else {
        int b = blk - NOUT, w = threadIdx.x;
        const int* row = b2t + (size_t)b * T_SUB;
        int lo = 0, hi = T_SUB;
        while (lo < hi) { int m = (lo + hi) >> 1; if (row[m] < w) lo = m + 1; else hi = m; }
        int lo2 = lo, hi2 = T_SUB;
        while (lo2 < hi2) { int m = (lo2 + hi2) >> 1; if (row[m] < w + 1) lo2 = m + 1; else hi2 = m; }
        seg[(size_t)b * WW + w] = make_int2(lo, lo2 - lo);
    }
}

// ---------------- K1: streaming mean -> fp16 x (R19-proven: seg from table) -
__global__ __launch_bounds__(256) void k_mean(
    const float* __restrict__ hiddens, const int2* __restrict__ seg,
    const int* __restrict__ cap_inds, const float* __restrict__ cap_table,
    _Float16* __restrict__ x)
{
    int idx = blockIdx.x * 256 + threadIdx.x;   // 16384*50 total
    int d2 = idx % 50;
    int bw = idx / 50;
    int b = bw >> 8;
    int2 sg = seg[bw];
    int lo = sg.x, cnt = sg.y;
    const size_t LSTR = (size_t)BB * (T_SUB + 1) * DD;
    const float* rowp = hiddens + ((size_t)b * (T_SUB + 1) + lo + 1) * DD;
    float inv = 1.0f / (3.0f * (float)(cnt > 0 ? cnt : 1));
    bool bmean = (d2 + 50) < 96;
    f16x8 ra, rb;

    if (cnt == 2 && bmean) {
        const float* pa  = rowp + d2 * 8;
        const float* pb_ = rowp + (d2 + 50) * 8;
        float4 A0 = *(const float4*)(pa);                float4 A1 = *(const float4*)(pa + 4);
        float4 A2 = *(const float4*)(pa + DD);           float4 A3 = *(const float4*)(pa + DD + 4);
        float4 A4 = *(const float4*)(pa + LSTR);         float4 A5 = *(const float4*)(pa + LSTR + 4);
        float4 A6 = *(const float4*)(pa + LSTR + DD);    float4 A7 = *(const float4*)(pa + LSTR + DD + 4);
        float4 A8 = *(const float4*)(pa + 2*LSTR);       float4 A9 = *(const float4*)(pa + 2*LSTR + 4);
        float4 Aa = *(const float4*)(pa + 2*LSTR + DD);  float4 Ab = *(const float4*)(pa + 2*LSTR + DD + 4);
        float4 B0 = *(const float4*)(pb_);               float4 B1 = *(const float4*)(pb_ + 4);
        float4 B2 = *(const float4*)(pb_ + DD);          float4 B3 = *(const float4*)(pb_ + DD + 4);
        float4 B4 = *(const float4*)(pb_ + LSTR);        float4 B5 = *(const float4*)(pb_ + LSTR + 4);
        float4 B6 = *(const float4*)(pb_ + LSTR + DD);   float4 B7 = *(const float4*)(pb_ + LSTR + DD + 4);
        float4 B8 = *(const float4*)(pb_ + 2*LSTR);      float4 B9 = *(const float4*)(pb_ + 2*LSTR + 4);
        float4 Ba = *(const float4*)(pb_ + 2*LSTR + DD); float4 Bb = *(const float4*)(pb_ + 2*LSTR + DD + 4);
        ra[0] = (_Float16)((A0.x+A2.x+A4.x+A6.x+A8.x+Aa.x) * inv);
        ra[1] = (_Float16)((A0.y+A2.y+A4.y+A6.y+A8.y+Aa.y) * inv);
        ra[2] = (_Float16)((A0.z+A2.z+A4.z+A6.z+A8.z+Aa.z) * inv);
        ra[3] = (_Float16)((A0.w+A2.w+A4.w+A6.w+A8.w+Aa.w) * inv);
        ra[4] = (_Float16)((A1.x+A3.x+A5.x+A7.x+A9.x+Ab.x) * inv);
        ra[5] = (_Float16)((A1.y+A3.y+A5.y+A7.y+A9.y+Ab.y) * inv);
        ra[6] = (_Float16)((A1.z+A3.z+A5.z+A7.z+A9.z+Ab.z) * inv);
        ra[7] = (_Float16)((A1.w+A3.w+A5.w+A7.w+A9.w+Ab.w) * inv);
        rb[0] = (_Float16)((B0.x+B2.x+B4.x+B6.x+B8.x+Ba.x) * inv);
        rb[1] = (_Float16)((B0.y+B2.y+B4.y+B6.y+B8.y+Ba.y) * inv);
        rb[2] = (_Float16)((B0.z+B2.z+B4.z+B6.z+B8.z+Ba.z) * inv);
        rb[3] = (_Float16)((B0.w+B2.w+B4.w+B6.w+B8.w+Ba.w) * inv);
        rb[4] = (_Float16)((B1.x+B3.x+B5.x+B7.x+B9.x+Bb.x) * inv);
        rb[5] = (_Float16)((B1.y+B3.y+B5.y+B7.y+B9.y+Bb.y) * inv);
        rb[6] = (_Float16)((B1.z+B3.z+B5.z+B7.z+B9.z+Bb.z) * inv);
        rb[7] = (_Float16)((B1.w+B3.w+B5.w+B7.w+B9.w+Bb.w) * inv);
    } else {
        float a[8], bacc[8];
#pragma unroll
        for (int q = 0; q < 8; q++) { a[q] = 0.f; bacc[q] = 0.f; }
        for (int l = 0; l < 3; ++l)
            for (int ti = 0; ti < cnt; ++ti) {
                const float* p = rowp + l * LSTR + (size_t)ti * DD;
                float4 v0 = *(const float4*)(p + d2 * 8);
                float4 v1 = *(const float4*)(p + d2 * 8 + 4);
                a[0]+=v0.x; a[1]+=v0.y; a[2]+=v0.z; a[3]+=v0.w;
                a[4]+=v1.x; a[5]+=v1.y; a[6]+=v1.z; a[7]+=v1.w;
                if (bmean) {
                    float4 u0 = *(const float4*)(p + (d2 + 50) * 8);
                    float4 u1 = *(const float4*)(p + (d2 + 50) * 8 + 4);
                    bacc[0]+=u0.x; bacc[1]+=u0.y; bacc[2]+=u0.z; bacc[3]+=u0.w;
                    bacc[4]+=u1.x; bacc[5]+=u1.y; bacc[6]+=u1.z; bacc[7]+=u1.w;
                }
            }
#pragma unroll
        for (int q = 0; q < 8; q++) { ra[q] = (_Float16)(a[q] * inv); rb[q] = (_Float16)(bacc[q] * inv); }
    }
    if (!bmean) {
        int ci = cap_inds[bw];
#pragma unroll
        for (int q = 0; q < 8; q++) {
            int c = (d2 + 50 - 96) * 8 + q;
            rb[q] = (c < CAP_DIM) ? (_Float16)cap_table[ci * CAP_DIM + c] : (_Float16)0.f;
        }
    }
    *(f16x8*)(x + (size_t)bw * KPAD + d2 * 8) = ra;
    *(f16x8*)(x + (size_t)bw * KPAD + (d2 + 50) * 8) = rb;
}

// ---------------- K2: FUSED gemm+LSTM, all-chunks-upfront, solo chain -------
__device__ __forceinline__ float xchg32(float v) {
    unsigned int a = __float_as_uint(v);
    uint2v r = __builtin_amdgcn_permlane32_swap(a, a, false, false);
    return __uint_as_float(r[0] ^ r[1] ^ a);   // partner lane's value (lane ^ 32)
}
__device__ __forceinline__ float fex2(float v) { return __builtin_amdgcn_exp2f(v); }
__device__ __forceinline__ float frcp(float v) { return __builtin_amdgcn_rcpf(v); }
__device__ __forceinline__ float rl(float v, int k) {
    return __uint_as_float(__builtin_amdgcn_readlane(__float_as_uint(v), k));
}

__global__ __launch_bounds__(320) void k_lstm(
    const _Float16* __restrict__ x, const _Float16* __restrict__ wp,
    const float* __restrict__ bias_f, const float* __restrict__ bias_b,
    const float* __restrict__ whh_f, const float* __restrict__ whh_b,
    float* __restrict__ out)
{
    __shared__ _Float16 gb[WW * G4];     // 40 KB: all 256 words' gates (f16)
    int dir  = blockIdx.x >> 6;
    int b    = blockIdx.x & 63;
    int t    = threadIdx.x;
    int wv   = t >> 6;
    int lane = t & 63;

    if (wv >= 1) {
        // ---- gemm: wave wv owns words [64*(wv-1), 64*wv), all 4 mtiles ----
        int col  = lane & 15;
        int koff = (lane >> 4) * 8;
        int wbase = (wv - 1) * 64;
        const _Float16* bp = wp + (size_t)(dir * G4 + col) * KPAD + koff;
        float bias_v[5];
#pragma unroll
        for (int nf = 0; nf < 5; nf++)
            bias_v[nf] = LOG2E * (dir ? bias_b : bias_f)[nf * 16 + col];
        f32x4 acc[4][5];
#pragma unroll
        for (int mt = 0; mt < 4; mt++)
#pragma unroll
            for (int nf = 0; nf < 5; nf++)
#pragma unroll
                for (int r = 0; r < 4; r++) acc[mt][nf][r] = 0.f;
        for (int k0 = 0; k0 < KPAD; k0 += 32) {
            f16x8 bf[5];
#pragma unroll
            for (int nf = 0; nf < 5; nf++)
                bf[nf] = *(const f16x8*)(bp + (size_t)nf * 16 * KPAD + k0);
#pragma unroll
            for (int mt = 0; mt < 4; mt++) {
                int arow = b * 256 + wbase + mt * 16 + (lane & 15);
                f16x8 af = *(const f16x8*)(x + (size_t)arow * KPAD + koff + k0);
#pragma unroll
                for (int nf = 0; nf < 5; nf++)
                    acc[mt][nf] = __builtin_amdgcn_mfma_f32_16x16x32_f16(af, bf[nf], acc[mt][nf], 0, 0, 0);
            }
        }
        // C/D: col=lane&15, row=(lane>>4)*4+reg [m89]. Permute cols + bias.
#pragma unroll
        for (int mt = 0; mt < 4; mt++)
#pragma unroll
            for (int nf = 0; nf < 5; nf++) {
                int g = nf * 16 + col;
                int pcol = (g % 40) * 2 + (g / 40);
#pragma unroll
                for (int r = 0; r < 4; r++) {
                    int word = wbase + mt * 16 + (lane >> 4) * 4 + r;
                    gb[word * G4 + pcol] = (_Float16)(acc[mt][nf][r] + bias_v[nf]);
                }
            }
        __syncthreads();   // single barrier; gemm waves exit
        return;
    }

    // ---- wave 0: recurrence constants ----
    const float* whh = dir ? whh_b : whh_f;
    int j = lane & 31; if (j > 19) j = 19;
    bool low = lane < 32;
    float mm = low ? 1.f : 2.f;
    float aa = low ? 0.f : -1.f;
    int coff = low ? (40 + 2 * j) : (2 * j);   // (f,o) | (i,g) pair, f16x2
    float w0[HH], w1[HH];
    {
        int r0 = low ? (20 + j) : j;
        int r1 = low ? (60 + j) : (40 + j);
#pragma unroll
        for (int k = 0; k < HH; k++) {
            w0[k] = LOG2E * whh[r0 * HH + k];
            w1[k] = LOG2E * whh[r1 * HH + k];
        }
    }
    __syncthreads();       // gates ready

    __builtin_amdgcn_s_setprio(1);
    const float TCM = -2.f * LOG2E;
    float h = 0.f, c = 0.f;
    int w = dir ? (WW - 1) : 0;
    int stepd = dir ? -1 : 1;

    union { unsigned int u; _Float16 hx[2]; } cu;
    cu.u = *(const unsigned int*)(gb + w * G4 + coff);
    float2 pre = make_float2((float)cu.hx[0], (float)cu.hx[1]);

    for (int sl = 0; sl < WW; ++sl) {
        int wn = w + stepd;
        int wnc = wn < 0 ? 0 : (wn > 255 ? 255 : wn);
        union { unsigned int u; _Float16 hx[2]; } nu;
        nu.u = *(const unsigned int*)(gb + wnc * G4 + coff);   // prefetch
        // 4-way split dot: 5-deep FMA chains
        float s0 = pre.x, s1 = 0.f, s2 = 0.f, s3 = 0.f;
        float t0 = pre.y, t1 = 0.f, t2 = 0.f, t3 = 0.f;
#pragma unroll
        for (int k = 0; k < 5; k++) {
            float h0 = rl(h, k), h1 = rl(h, k + 5), h2 = rl(h, k + 10), h3 = rl(h, k + 15);
            s0 = fmaf(h0, w0[k],      s0);  s1 = fmaf(h1, w0[k + 5],  s1);
            s2 = fmaf(h2, w0[k + 10], s2);  s3 = fmaf(h3, w0[k + 15], s3);
            t0 = fmaf(h0, w1[k],      t0);  t1 = fmaf(h1, w1[k + 5],  t1);
            t2 = fmaf(h2, w1[k + 10], t2);  t3 = fmaf(h3, w1[k + 15], t3);
        }
        float a0 = (s0 + s1) + (s2 + s3);
        float a1 = (t0 + t1) + (t2 + t3);
        float u0 = frcp(1.f + fex2(-a0));              // sig(f) | sig(i)
        float uu = frcp(1.f + fex2(-mm * a1));
        float u1 = fmaf(uu, mm, aa);                   // sig(o) | tanh(g)
        float p  = u0 * u1;
        float ps = xchg32(p);                          // low gets sig(i)*tanh(g)
        c = fmaf(u0, c, ps);
        float tc = fmaf(2.f, frcp(1.f + fex2(TCM * c)), -1.f);  // tanh(c)
        h = u1 * tc;
        if (lane < HH)
            out[((size_t)b * WW + w) * (2 * HH) + dir * HH + lane] = h;
        pre = make_float2((float)nu.hx[0], (float)nu.hx[1]);
        w = wn;
    }
    __builtin_amdgcn_s_setprio(0);
}

extern "C" void kernel_launch(void* const* d_in, const int* in_sizes, int n_in,
                              void* d_out, int out_size, void* d_ws, size_t ws_size,
                              hipStream_t stream) {
    const float* hiddens   = (const float*)d_in[0];
    const int*   bert2toks = (const int*)d_in[1];
    const int*   cap_inds  = (const int*)d_in[2];
    const float* cap_table = (const float*)d_in[3];
    const float* w_ih_f    = (const float*)d_in[4];
    const float* w_hh_f    = (const float*)d_in[5];
    const float* b_f       = (const float*)d_in[6];
    const float* w_ih_b    = (const float*)d_in[7];
    const float* w_hh_b    = (const float*)d_in[8];
    const float* b_b       = (const float*)d_in[9];
    float* out = (float*)d_out;

    _Float16* wpad = (_Float16*)((char*)d_ws + WP_OFF);
    int2*     seg  = (int2*)((char*)d_ws + SEG_OFF);
    _Float16* x    = (_Float16*)((char*)d_ws + X_OFF);

    k_prep<<<NOUT + BB, 256, 0, stream>>>(w_ih_f, w_ih_b, bert2toks, wpad, seg);
    k_mean<<<(BB * WW * 50) / 256, 256, 0, stream>>>(hiddens, seg, cap_inds, cap_table, x);
    k_lstm<<<128, 320, 0, stream>>>(x, wpad, b_f, b_b, w_hh_f, w_hh_b, out);
}

// Round 23
// 133.915 us; speedup vs baseline: 1.2808x; 1.0361x over previous
//
#include <hip/hip_runtime.h>
#include <math.h>

#define BB 64
#define T_SUB 512
#define WW 256
#define DD 768
#define HH 20
#define CAP_DIM 10
#define IN_DIM 778
#define KPAD 800
#define G4 80     // 4*H
#define NOUT 160
#define LOG2E 1.44269504f

typedef _Float16 f16x8 __attribute__((ext_vector_type(8)));
typedef float f32x4 __attribute__((ext_vector_type(4)));
typedef unsigned int uint2v __attribute__((ext_vector_type(2)));

// ws layout (bytes):
//   wpad : [160][800] f16   @ 0          (256,000 B)  -- PRE-SCALED by log2e
//   seg  : int2[16384]      @ 256,000    (131,072 B)
//   x    : [16384][800] f16 @ 387,072    (26,214,400 B)
#define WP_OFF   ((size_t)0)
#define SEG_OFF  ((size_t)256000)
#define X_OFF    ((size_t)387072)

// ---------------- K0: pad+scale weights (0..159) + segment search (160..223)
__global__ __launch_bounds__(256) void k_prep(
    const float* __restrict__ wf, const float* __restrict__ wb,
    const int* __restrict__ b2t,
    _Float16* __restrict__ wp, int2* __restrict__ seg)
{
    int blk = blockIdx.x;
    if (blk < NOUT) {
        int j = blk;
        const float* src = (j < G4) ? (wf + (size_t)j * IN_DIM)
                                    : (wb + (size_t)(j - G4) * IN_DIM);
        for (int k = threadIdx.x; k < KPAD; k += 256)
            wp[(size_t)j * KPAD + k] = (k < IN_DIM) ? (_Float16)(LOG2E * src[k])
                                                    : (_Float16)0.f;
    } else {
        int b = blk - NOUT, w = threadIdx.x;
        const int* row = b2t + (size_t)b * T_SUB;
        int lo = 0, hi = T_SUB;
        while (lo < hi) { int m = (lo + hi) >> 1; if (row[m] < w) lo = m + 1; else hi = m; }
        int lo2 = lo, hi2 = T_SUB;
        while (lo2 < hi2) { int m = (lo2 + hi2) >> 1; if (row[m] < w + 1) lo2 = m + 1; else hi2 = m; }
        seg[(size_t)b * WW + w] = make_int2(lo, lo2 - lo);
    }
}

// ---------------- K1: streaming mean -> fp16 x (seg from table) -------------
__global__ __launch_bounds__(256) void k_mean(
    const float* __restrict__ hiddens, const int2* __restrict__ seg,
    const int* __restrict__ cap_inds, const float* __restrict__ cap_table,
    _Float16* __restrict__ x)
{
    int idx = blockIdx.x * 256 + threadIdx.x;   // 16384*50 total
    int d2 = idx % 50;
    int bw = idx / 50;
    int b = bw >> 8;
    int2 sg = seg[bw];
    int lo = sg.x, cnt = sg.y;
    const size_t LSTR = (size_t)BB * (T_SUB + 1) * DD;
    const float* rowp = hiddens + ((size_t)b * (T_SUB + 1) + lo + 1) * DD;
    float inv = 1.0f / (3.0f * (float)(cnt > 0 ? cnt : 1));
    bool bmean = (d2 + 50) < 96;
    f16x8 ra, rb;

    if (cnt == 2 && bmean) {
        const float* pa  = rowp + d2 * 8;
        const float* pb_ = rowp + (d2 + 50) * 8;
        float4 A0 = *(const float4*)(pa);                float4 A1 = *(const float4*)(pa + 4);
        float4 A2 = *(const float4*)(pa + DD);           float4 A3 = *(const float4*)(pa + DD + 4);
        float4 A4 = *(const float4*)(pa + LSTR);         float4 A5 = *(const float4*)(pa + LSTR + 4);
        float4 A6 = *(const float4*)(pa + LSTR + DD);    float4 A7 = *(const float4*)(pa + LSTR + DD + 4);
        float4 A8 = *(const float4*)(pa + 2*LSTR);       float4 A9 = *(const float4*)(pa + 2*LSTR + 4);
        float4 Aa = *(const float4*)(pa + 2*LSTR + DD);  float4 Ab = *(const float4*)(pa + 2*LSTR + DD + 4);
        float4 B0 = *(const float4*)(pb_);               float4 B1 = *(const float4*)(pb_ + 4);
        float4 B2 = *(const float4*)(pb_ + DD);          float4 B3 = *(const float4*)(pb_ + DD + 4);
        float4 B4 = *(const float4*)(pb_ + LSTR);        float4 B5 = *(const float4*)(pb_ + LSTR + 4);
        float4 B6 = *(const float4*)(pb_ + LSTR + DD);   float4 B7 = *(const float4*)(pb_ + LSTR + DD + 4);
        float4 B8 = *(const float4*)(pb_ + 2*LSTR);      float4 B9 = *(const float4*)(pb_ + 2*LSTR + 4);
        float4 Ba = *(const float4*)(pb_ + 2*LSTR + DD); float4 Bb = *(const float4*)(pb_ + 2*LSTR + DD + 4);
        ra[0] = (_Float16)((A0.x+A2.x+A4.x+A6.x+A8.x+Aa.x) * inv);
        ra[1] = (_Float16)((A0.y+A2.y+A4.y+A6.y+A8.y+Aa.y) * inv);
        ra[2] = (_Float16)((A0.z+A2.z+A4.z+A6.z+A8.z+Aa.z) * inv);
        ra[3] = (_Float16)((A0.w+A2.w+A4.w+A6.w+A8.w+Aa.w) * inv);
        ra[4] = (_Float16)((A1.x+A3.x+A5.x+A7.x+A9.x+Ab.x) * inv);
        ra[5] = (_Float16)((A1.y+A3.y+A5.y+A7.y+A9.y+Ab.y) * inv);
        ra[6] = (_Float16)((A1.z+A3.z+A5.z+A7.z+A9.z+Ab.z) * inv);
        ra[7] = (_Float16)((A1.w+A3.w+A5.w+A7.w+A9.w+Ab.w) * inv);
        rb[0] = (_Float16)((B0.x+B2.x+B4.x+B6.x+B8.x+Ba.x) * inv);
        rb[1] = (_Float16)((B0.y+B2.y+B4.y+B6.y+B8.y+Ba.y) * inv);
        rb[2] = (_Float16)((B0.z+B2.z+B4.z+B6.z+B8.z+Ba.z) * inv);
        rb[3] = (_Float16)((B0.w+B2.w+B4.w+B6.w+B8.w+Ba.w) * inv);
        rb[4] = (_Float16)((B1.x+B3.x+B5.x+B7.x+B9.x+Bb.x) * inv);
        rb[5] = (_Float16)((B1.y+B3.y+B5.y+B7.y+B9.y+Bb.y) * inv);
        rb[6] = (_Float16)((B1.z+B3.z+B5.z+B7.z+B9.z+Bb.z) * inv);
        rb[7] = (_Float16)((B1.w+B3.w+B5.w+B7.w+B9.w+Bb.w) * inv);
    } else {
        float a[8], bacc[8];
#pragma unroll
        for (int q = 0; q < 8; q++) { a[q] = 0.f; bacc[q] = 0.f; }
        for (int l = 0; l < 3; ++l)
            for (int ti = 0; ti < cnt; ++ti) {
                const float* p = rowp + l * LSTR + (size_t)ti * DD;
                float4 v0 = *(const float4*)(p + d2 * 8);
                float4 v1 = *(const float4*)(p + d2 * 8 + 4);
                a[0]+=v0.x; a[1]+=v0.y; a[2]+=v0.z; a[3]+=v0.w;
                a[4]+=v1.x; a[5]+=v1.y; a[6]+=v1.z; a[7]+=v1.w;
                if (bmean) {
                    float4 u0 = *(const float4*)(p + (d2 + 50) * 8);
                    float4 u1 = *(const float4*)(p + (d2 + 50) * 8 + 4);
                    bacc[0]+=u0.x; bacc[1]+=u0.y; bacc[2]+=u0.z; bacc[3]+=u0.w;
                    bacc[4]+=u1.x; bacc[5]+=u1.y; bacc[6]+=u1.z; bacc[7]+=u1.w;
                }
            }
#pragma unroll
        for (int q = 0; q < 8; q++) { ra[q] = (_Float16)(a[q] * inv); rb[q] = (_Float16)(bacc[q] * inv); }
    }
    if (!bmean) {
        int ci = cap_inds[bw];
#pragma unroll
        for (int q = 0; q < 8; q++) {
            int c = (d2 + 50 - 96) * 8 + q;
            rb[q] = (c < CAP_DIM) ? (_Float16)cap_table[ci * CAP_DIM + c] : (_Float16)0.f;
        }
    }
    *(f16x8*)(x + (size_t)bw * KPAD + d2 * 8) = ra;
    *(f16x8*)(x + (size_t)bw * KPAD + (d2 + 50) * 8) = rb;
}

// ---------------- K2: FUSED gemm+LSTM, all-chunks-upfront, solo chain -------
__device__ __forceinline__ float xchg32(float v) {
    unsigned int a = __float_as_uint(v);
    uint2v r = __builtin_amdgcn_permlane32_swap(a, a, false, false);
    return __uint_as_float(r[0] ^ r[1] ^ a);   // partner lane's value (lane ^ 32)
}
__device__ __forceinline__ float fex2(float v) { return __builtin_amdgcn_exp2f(v); }
__device__ __forceinline__ float frcp(float v) { return __builtin_amdgcn_rcpf(v); }
__device__ __forceinline__ float rl(float v, int k) {
    return __uint_as_float(__builtin_amdgcn_readlane(__float_as_uint(v), k));
}

__global__ __launch_bounds__(320) void k_lstm(
    const _Float16* __restrict__ x, const _Float16* __restrict__ wp,
    const float* __restrict__ bias_f, const float* __restrict__ bias_b,
    const float* __restrict__ whh_f, const float* __restrict__ whh_b,
    float* __restrict__ out)
{
    __shared__ _Float16 gb[WW * G4];     // 40 KB: all 256 words' gates (f16)
    int dir  = blockIdx.x >> 6;
    int b    = blockIdx.x & 63;
    int t    = threadIdx.x;
    int wv   = t >> 6;
    int lane = t & 63;

    if (wv >= 1) {
        // ---- gemm: wave wv owns words [64*(wv-1), 64*wv), all 4 mtiles ----
        int col  = lane & 15;
        int koff = (lane >> 4) * 8;
        int wbase = (wv - 1) * 64;
        const _Float16* bp = wp + (size_t)(dir * G4 + col) * KPAD + koff;
        float bias_v[5];
#pragma unroll
        for (int nf = 0; nf < 5; nf++)
            bias_v[nf] = LOG2E * (dir ? bias_b : bias_f)[nf * 16 + col];
        f32x4 acc[4][5];
#pragma unroll
        for (int mt = 0; mt < 4; mt++)
#pragma unroll
            for (int nf = 0; nf < 5; nf++)
#pragma unroll
                for (int r = 0; r < 4; r++) acc[mt][nf][r] = 0.f;
        for (int k0 = 0; k0 < KPAD; k0 += 32) {
            f16x8 bf[5];
#pragma unroll
            for (int nf = 0; nf < 5; nf++)
                bf[nf] = *(const f16x8*)(bp + (size_t)nf * 16 * KPAD + k0);
#pragma unroll
            for (int mt = 0; mt < 4; mt++) {
                int arow = b * 256 + wbase + mt * 16 + (lane & 15);
                f16x8 af = *(const f16x8*)(x + (size_t)arow * KPAD + koff + k0);
#pragma unroll
                for (int nf = 0; nf < 5; nf++)
                    acc[mt][nf] = __builtin_amdgcn_mfma_f32_16x16x32_f16(af, bf[nf], acc[mt][nf], 0, 0, 0);
            }
        }
        // C/D: col=lane&15, row=(lane>>4)*4+reg [m89]. Permute cols + bias.
#pragma unroll
        for (int mt = 0; mt < 4; mt++)
#pragma unroll
            for (int nf = 0; nf < 5; nf++) {
                int g = nf * 16 + col;
                int pcol = (g % 40) * 2 + (g / 40);
#pragma unroll
                for (int r = 0; r < 4; r++) {
                    int word = wbase + mt * 16 + (lane >> 4) * 4 + r;
                    gb[word * G4 + pcol] = (_Float16)(acc[mt][nf][r] + bias_v[nf]);
                }
            }
        __syncthreads();   // single barrier; gemm waves exit
        return;
    }

    // ---- wave 0: recurrence constants ----
    const float* whh = dir ? whh_b : whh_f;
    int j = lane & 31; if (j > 19) j = 19;
    bool low = lane < 32;
    float mm = low ? 1.f : 2.f;
    float aa = low ? 0.f : -1.f;
    int coff = low ? (40 + 2 * j) : (2 * j);   // (f,o) | (i,g) pair, f16x2
    float w0[HH], w1[HH];
    {
        int r0 = low ? (20 + j) : j;
        int r1 = low ? (60 + j) : (40 + j);
#pragma unroll
        for (int k = 0; k < HH; k++) {
            w0[k] = LOG2E * whh[r0 * HH + k];
            w1[k] = LOG2E * whh[r1 * HH + k];
        }
    }
    __syncthreads();       // gates ready

    __builtin_amdgcn_s_setprio(1);
    const float TCM = -2.f * LOG2E;
    float h = 0.f, c = 0.f;
    int w = dir ? (WW - 1) : 0;
    int stepd = dir ? -1 : 1;

    union { unsigned int u; _Float16 hx[2]; } cu;
    cu.u = *(const unsigned int*)(gb + w * G4 + coff);
    float2 pre = make_float2((float)cu.hx[0], (float)cu.hx[1]);

    for (int sl = 0; sl < WW; ++sl) {
        int wn = w + stepd;
        int wnc = wn < 0 ? 0 : (wn > 255 ? 255 : wn);
        union { unsigned int u; _Float16 hx[2]; } nu;
        nu.u = *(const unsigned int*)(gb + wnc * G4 + coff);   // prefetch
        // 2-way split dot (best-measured R19 config)
        float a0a = pre.x, a0b = 0.f, a1a = pre.y, a1b = 0.f;
#pragma unroll
        for (int k = 0; k < 10; k++) {
            float hk  = rl(h, k);
            float hk2 = rl(h, k + 10);
            a0a = fmaf(hk,  w0[k],      a0a);
            a1a = fmaf(hk,  w1[k],      a1a);
            a0b = fmaf(hk2, w0[k + 10], a0b);
            a1b = fmaf(hk2, w1[k + 10], a1b);
        }
        float a0 = a0a + a0b, a1 = a1a + a1b;
        float u0 = frcp(1.f + fex2(-a0));              // sig(f) | sig(i)
        float uu = frcp(1.f + fex2(-mm * a1));
        float u1 = fmaf(uu, mm, aa);                   // sig(o) | tanh(g)
        float p  = u0 * u1;
        float ps = xchg32(p);                          // low gets sig(i)*tanh(g)
        c = fmaf(u0, c, ps);
        float tc = fmaf(2.f, frcp(1.f + fex2(TCM * c)), -1.f);  // tanh(c)
        h = u1 * tc;
        if (lane < HH)
            out[((size_t)b * WW + w) * (2 * HH) + dir * HH + lane] = h;
        pre = make_float2((float)nu.hx[0], (float)nu.hx[1]);
        w = wn;
    }
    __builtin_amdgcn_s_setprio(0);
}

extern "C" void kernel_launch(void* const* d_in, const int* in_sizes, int n_in,
                              void* d_out, int out_size, void* d_ws, size_t ws_size,
                              hipStream_t stream) {
    const float* hiddens   = (const float*)d_in[0];
    const int*   bert2toks = (const int*)d_in[1];
    const int*   cap_inds  = (const int*)d_in[2];
    const float* cap_table = (const float*)d_in[3];
    const float* w_ih_f    = (const float*)d_in[4];
    const float* w_hh_f    = (const float*)d_in[5];
    const float* b_f       = (const float*)d_in[6];
    const float* w_ih_b    = (const float*)d_in[7];
    const float* w_hh_b    = (const float*)d_in[8];
    const float* b_b       = (const float*)d_in[9];
    float* out = (float*)d_out;

    _Float16* wpad = (_Float16*)((char*)d_ws + WP_OFF);
    int2*     seg  = (int2*)((char*)d_ws + SEG_OFF);
    _Float16* x    = (_Float16*)((char*)d_ws + X_OFF);

    k_prep<<<NOUT + BB, 256, 0, stream>>>(w_ih_f, w_ih_b, bert2toks, wpad, seg);
    k_mean<<<(BB * WW * 50) / 256, 256, 0, stream>>>(hiddens, seg, cap_inds, cap_table, x);
    k_lstm<<<128, 320, 0, stream>>>(x, wpad, b_f, b_b, w_hh_f, w_hh_b, out);
}